// Round 2
// 856.572 us; speedup vs baseline: 1.0083x; 1.0083x over previous
//
#include <hip/hip_runtime.h>
#include <hip/hip_bf16.h>
#include <stdint.h>
#include <math.h>

typedef uint32_t u32;
typedef __hip_bfloat16 bf16t;
typedef __attribute__((ext_vector_type(8))) short short8;
typedef __attribute__((ext_vector_type(4))) float f32x4;

// JAX PRNG: threefry2x32, jax_threefry_partitionable=True semantics (verified R2):
//   split(key,n)[i] = (o0(key;0,i), o1(key;0,i))
//   random_bits32(key,shape)[f] = o0(key;0,f) ^ o1(key;0,f)
//   randint pre-splits its key, uses subkey2; span 8192 pow2 -> bits & 8191
//   fold_in(key,d) = threefry(key,(0,d))

// ================= threefry2x32 (bit-exact vs JAX) =================
__host__ __device__ __forceinline__ void tf2(u32 k0, u32 k1, u32 c0, u32 c1, u32& o0, u32& o1) {
  const u32 ks2 = k0 ^ k1 ^ 0x1BD11BDAu;
  u32 x0 = c0 + k0, x1 = c1 + k1;
#define TFROT(v,r) (((v)<<(r))|((v)>>(32-(r))))
#define TFR(r) { x0 += x1; x1 = TFROT(x1,r); x1 ^= x0; }
  TFR(13) TFR(15) TFR(26) TFR(6)   x0 += k1;  x1 += ks2 + 1u;
  TFR(17) TFR(29) TFR(16) TFR(24)  x0 += ks2; x1 += k0 + 2u;
  TFR(13) TFR(15) TFR(26) TFR(6)   x0 += k0;  x1 += k1 + 3u;
  TFR(17) TFR(29) TFR(16) TFR(24)  x0 += k1;  x1 += ks2 + 4u;
  TFR(13) TFR(15) TFR(26) TFR(6)   x0 += ks2; x1 += k0 + 5u;
#undef TFR
#undef TFROT
  o0 = x0; o1 = x1;
}

__device__ __forceinline__ float unif_row(u32 ka, u32 kb, int i) {
  u32 o0, o1;
  tf2(ka, kb, 0u, (u32)i, o0, o1);
  return __uint_as_float(0x3F800000u | ((o0 ^ o1) >> 9)) - 1.0f;
}

__device__ __forceinline__ int ridx_fn(u32 ka, u32 kb, u32 f) {
  u32 o0, o1; tf2(ka, kb, 0u, f, o0, o1); return (int)((o0 ^ o1) & 8191u);
}

static inline void split2(u32 ka, u32 kb, u32* kA, u32* kB) {
  u32 a0, a1, b0, b1;
  tf2(ka, kb, 0u, 0u, a0, a1);
  tf2(ka, kb, 0u, 1u, b0, b1);
  kA[0] = a0; kA[1] = a1; kB[0] = b0; kB[1] = b1;
}

static inline void split6(u32 ka, u32 kb, u32 out[6][2]) {
  for (u32 i = 0; i < 6; i++) { u32 o0, o1; tf2(ka, kb, 0u, i, o0, o1); out[i][0] = o0; out[i][1] = o1; }
}

static inline int scalar_randint8192(u32 ka, u32 kb) {
  u32 kA[2], kB[2];
  split2(ka, kb, kA, kB);
  u32 o0, o1;
  tf2(kB[0], kB[1], 0u, 0u, o0, o1);
  return (int)((o0 ^ o1) & 8191u);
}

__device__ __forceinline__ ushort f2bf(float f) {  // f32 -> bf16 RNE
  u32 u = __float_as_uint(f);
  u32 r = u + 0x7FFFu + ((u >> 16) & 1u);
  return (ushort)(r >> 16);
}

// ================= packing kernels =================
// pack B[K][Nn] f32 row-major -> bf16 [(k>>3)*Nn + n]*8 + (k&7)
__global__ __launch_bounds__(256) void packb_k(const float* __restrict__ B, uint4* __restrict__ out, int K, int Nn) {
  const int idx = blockIdx.x * 256 + threadIdx.x;
  const int total = (K >> 3) * Nn;
  if (idx >= total) return;
  const int g = idx / Nn;
  const int n = idx - g * Nn;
  u32 wv[4];
#pragma unroll
  for (int j = 0; j < 4; j++) {
    const float f0 = B[(size_t)(g * 8 + 2 * j) * Nn + n];
    const float f1 = B[(size_t)(g * 8 + 2 * j + 1) * Nn + n];
    wv[j] = (u32)f2bf(f0) | ((u32)f2bf(f1) << 16);
  }
  uint4 o; o.x = wv[0]; o.y = wv[1]; o.z = wv[2]; o.w = wv[3];
  out[idx] = o;
}

// pack A[M][K] f32 row-major -> bf16 GEMM A-tile image.
// chunk (cm = m>>7, s = k>>6) is 16KB, the exact LDS image for one 128x64 tile:
//   unit(16B) = r*8 + (kq ^ (r&7)),  r = m&127, kq = (k&63)>>3
// The XOR bakes the LDS bank-swizzle (byte ^= (row&7)<<4) into the packed layout,
// so global_load_lds stages it with a pure linear lane-contiguous copy (T2+m173:
// pre-swizzled source + swizzled read, LDS dest stays linear).
__global__ __launch_bounds__(256) void packa_k(const float* __restrict__ A, uint4* __restrict__ out,
                                               int M, int K, int lgS) {
  const int idx = blockIdx.x * 256 + threadIdx.x;
  const int S = K >> 6;
  const int total = ((M >> 7) * S) << 10;
  if (idx >= total) return;
  const int chunk = idx >> 10;
  const int w = idx & 1023;
  const int r = w >> 3, kq = w & 7;
  const int cm = chunk >> lgS, s = chunk & (S - 1);
  const float* src = A + (size_t)((cm << 7) + r) * K + (s << 6) + (kq << 3);
  const float4 f0 = *(const float4*)src;
  const float4 f1 = *(const float4*)(src + 4);
  u32 wv[4];
  wv[0] = (u32)f2bf(f0.x) | ((u32)f2bf(f0.y) << 16);
  wv[1] = (u32)f2bf(f0.z) | ((u32)f2bf(f0.w) << 16);
  wv[2] = (u32)f2bf(f1.x) | ((u32)f2bf(f1.y) << 16);
  wv[3] = (u32)f2bf(f1.z) | ((u32)f2bf(f1.w) << 16);
  uint4 o; o.x = wv[0]; o.y = wv[1]; o.z = wv[2]; o.w = wv[3];
  out[((size_t)chunk << 10) + (r << 3) + (kq ^ (r & 7))] = o;
}

__global__ __launch_bounds__(256) void minmax2_k(const float* __restrict__ part, int G, float* __restrict__ bnd) {
  __shared__ float slo[256], shi[256];
  const int tid = threadIdx.x;
  float lo = 3.4e38f, hi = -3.4e38f;
  for (int i = tid; i < G; i += 256) { lo = fminf(lo, part[i]); hi = fmaxf(hi, part[G + i]); }
  slo[tid] = lo; shi[tid] = hi; __syncthreads();
  for (int s = 128; s > 0; s >>= 1) {
    if (tid < s) { slo[tid] = fminf(slo[tid], slo[tid + s]); shi[tid] = fmaxf(shi[tid], shi[tid + s]); }
    __syncthreads();
  }
  if (tid == 0) { bnd[0] = slo[0]; bnd[1] = shi[0]; }
}

// ================= bf16 MFMA GEMM — m97 structure =================
// 256 threads / 4 waves, 2x2 wave grid of 64x64 tiles (acc[4][4]), BM=BN=128,
// BK=64, both operands staged via global_load_lds (A pre-packed+swizzled,
// B k-group-major), double-buffered LDS (64KB -> 2 blocks/CU), 1 barrier/step.
// LDS-read traffic: 16KB/wave/step = 32.8 FLOP/byte (1.5x the old 64x32 tiles),
// zero VALU on the A path (cvt moved to packa_k, done once not 8x).
__device__ __forceinline__ void gld_lds16(const void* g, void* l) {
  __builtin_amdgcn_global_load_lds((const __attribute__((address_space(1))) void*)g,
                                   (__attribute__((address_space(3))) void*)l, 16, 0, 0);
}

// EPI 1: C = (1-alpha)*acc + alpha*aux, + fused block min/max -> prt
// EPI 2: C = theta*acc + (1-theta)*aux, theta = log(lamda/l + 1)
// Grid: bm = blockIdx&63 (XCD = bm&7), bn = blockIdx>>6 — n-blocks of an A-panel
// share one XCD's L2.
template <int EPI>
__global__ __launch_bounds__(256, 2) void gemm_k(
    const bf16t* __restrict__ Ap, const bf16t* __restrict__ Bp,
    const float* __restrict__ aux, const float* __restrict__ sF,
    const int* __restrict__ sI, float* __restrict__ C,
    float* __restrict__ prt, int PG, int Nn, int K) {
  __shared__ __align__(16) bf16t As[2][8192];
  __shared__ __align__(16) bf16t Bs[2][8192];
  const int tid = threadIdx.x;
  const int lane = tid & 63;
  const int wave = tid >> 6;                 // 0..3
  const int bm = blockIdx.x & 63;
  const int bn = blockIdx.x >> 6;
  const int m0 = bm << 7, n0 = bn << 7;
  const int wm = (wave & 1) << 6;            // 0,64
  const int wn = (wave >> 1) << 6;           // 0,64
  const int S = K >> 6;

  f32x4 acc[4][4];
#pragma unroll
  for (int i = 0; i < 4; i++)
#pragma unroll
    for (int j = 0; j < 4; j++) acc[i][j] = (f32x4){0.f, 0.f, 0.f, 0.f};

  // staging: 1024 16B-units per tile; thread t owns units t + j*256, j=0..3
  // (lane-contiguous within each wave -> valid global_load_lds destinations)
  const bf16t* gA0 = Ap + (((size_t)bm * S) << 13);  // chunk (bm,s): 8192 bf16
  const bf16t* gBj[4];
  const size_t bstep = (size_t)Nn * 64;              // B elems per super-step
#pragma unroll
  for (int j = 0; j < 4; j++) {
    const int u = tid + (j << 8);
    gBj[j] = Bp + ((size_t)(u >> 7) * Nn + n0 + (u & 127)) * 8;
  }
  auto stage = [&](int s, int buf) {
    const bf16t* a = gA0 + ((size_t)s << 13);
#pragma unroll
    for (int j = 0; j < 4; j++) {
      const int u = tid + (j << 8);
      gld_lds16(a + ((size_t)u << 3), &As[buf][u << 3]);
    }
#pragma unroll
    for (int j = 0; j < 4; j++) {
      const int u = tid + (j << 8);
      gld_lds16(gBj[j] + (size_t)s * bstep, &Bs[buf][u << 3]);
    }
  };

  // frag read bases (bf16-element indices)
  const int arow = lane & 15, aq = lane >> 4;
  // A: elem = row*64 + ((kq ^ (row&7))<<3), row = wm+mt*16+arow, kq = c*4+aq
  //    row&7 == arow&7 -> swizzle term ((aq^(arow&7))<<3), c toggles elem bit 5
  const int abase = ((wm + arow) << 6) + ((aq ^ (arow & 7)) << 3);
  // B: elem = (kg*128 + col)*8, kg = c*4+aq, col = wn+nt*16+arow
  const int bbase = ((aq << 7) + wn + arow) << 3;

  // prologue: stage step 0 into buffer 0
  stage(0, 0);

  for (int s = 0; s < S; ++s) {
    const int cur = s & 1;
    __syncthreads();  // drains step-s prefetch (vmcnt), publishes buf[cur]
    if (s + 1 < S) stage(s + 1, cur ^ 1);
#pragma unroll
    for (int c = 0; c < 2; ++c) {
      short8 af[4], bv[4];
      const int ab = abase ^ (c << 5);
#pragma unroll
      for (int mt = 0; mt < 4; mt++)
        af[mt] = *(const short8*)(&As[cur][ab + mt * 1024]);
#pragma unroll
      for (int nt = 0; nt < 4; nt++)
        bv[nt] = *(const short8*)(&Bs[cur][bbase + (c << 12) + (nt << 7)]);
#pragma unroll
      for (int mt = 0; mt < 4; mt++)
#pragma unroll
        for (int nt = 0; nt < 4; nt++)
          acc[mt][nt] = __builtin_amdgcn_mfma_f32_16x16x32_bf16(af[mt], bv[nt], acc[mt][nt], 0, 0, 0);
    }
  }

  float p1, p2;
  if (EPI == 1) { const float al = sF[0]; p1 = 1.0f - al; p2 = al; }
  else { const float th = logf(sF[0] / (float)sI[0] + 1.0f); p1 = th; p2 = 1.0f - th; }
  const int col = lane & 15, rq = lane >> 4;
  float vlo = 3.4e38f, vhi = -3.4e38f;
#pragma unroll
  for (int mt = 0; mt < 4; mt++)
#pragma unroll
    for (int nt = 0; nt < 4; nt++)
#pragma unroll
      for (int r = 0; r < 4; r++) {
        const int gm = m0 + wm + mt * 16 + (rq << 2) + r;
        const int gn = n0 + wn + nt * 16 + col;
        const size_t ix = (size_t)gm * Nn + gn;
        const float v = p1 * acc[mt][nt][r] + p2 * aux[ix];
        C[ix] = v;
        if (EPI == 1) { vlo = fminf(vlo, v); vhi = fmaxf(vhi, v); }
      }
  if (EPI == 1) {  // fused block min/max -> partials
    __syncthreads();
    float* red = (float*)&As[0][0];
    red[tid] = vlo; red[256 + tid] = vhi;
    __syncthreads();
    for (int s = 128; s > 0; s >>= 1) {
      if (tid < s) {
        red[tid] = fminf(red[tid], red[tid + s]);
        red[256 + tid] = fmaxf(red[256 + tid], red[256 + tid + s]);
      }
      __syncthreads();
    }
    if (tid == 0) { prt[blockIdx.x] = red[0]; prt[PG + blockIdx.x] = red[256]; }
  }
}

// ================= whale optimizer step =================
struct WA {
  u32 k1a, k1b, k2a, k2b, k3a, k3b, k4a, k4b, k5a, k5b;
  int ldr;
  float a, a2;
};

__global__ __launch_bounds__(256) void whale_k(
    const float* __restrict__ pinb, float* __restrict__ poutb,
    ushort* __restrict__ opt, const float* __restrict__ bnd, WA w) {
  const int row = blockIdx.x;
  const int tid = threadIdx.x;
  __shared__ float sh[4];
  if (tid < 4) {
    u32 ka, kb;
    if (tid == 0)      { ka = w.k1a; kb = w.k1b; }
    else if (tid == 1) { ka = w.k2a; kb = w.k2b; }
    else if (tid == 2) { ka = w.k3a; kb = w.k3b; }
    else               { ka = w.k4a; kb = w.k4b; }
    sh[tid] = unif_row(ka, kb, row);
  }
  __syncthreads();
  const float r1 = sh[0], r2 = sh[1], u3 = sh[2], p = sh[3];
  // A feeds the |A|>=1 branch decision: match XLA's mul-then-sub (no fma contraction)
  float t2 = (2.0f * w.a) * r1;
  asm volatile("" : "+v"(t2));
  const float A = t2 - w.a;
  const float Cc = 2.0f * r2;
  const float lo = bnd[0], hi = bnd[1];
  const float* pin = pinb + ((size_t)row << 10);
  const int j0 = tid << 2;
  float4 pv = *(const float4*)(pin + j0);
  float ov[4];
  const bool bp = (p < 0.5f);
  if (bp && (fabsf(A) >= 1.0f)) {  // explore: per-element random-row gather
    const u32 fb = ((u32)row << 10) + (u32)j0;
#pragma unroll
    for (int e = 0; e < 4; e++) {
      const float pos = (&pv.x)[e];
      const int ri = ridx_fn(w.k5a, w.k5b, fb + (u32)e);
      const float xr = pinb[((size_t)ri << 10) + j0 + e];
      ov[e] = fabsf(xr - A * fabsf(Cc * xr - pos));
    }
  } else {
    const float* ldp = pinb + ((size_t)w.ldr << 10);
    float4 lv = *(const float4*)(ldp + j0);
    if (bp) {  // exploit
#pragma unroll
      for (int e = 0; e < 4; e++) {
        const float pos = (&pv.x)[e], ld = (&lv.x)[e];
        ov[e] = fabsf(ld - A * fabsf(Cc * ld - pos));
      }
    } else {  // spiral
      const float lp = (w.a2 - 1.0f) * u3 + 1.0f;
      const float s1 = expf(lp);
      const float s2 = cosf(6.2831855f * lp);
#pragma unroll
      for (int e = 0; e < 4; e++) {
        const float pos = (&pv.x)[e], ld = (&lv.x)[e];
        ov[e] = fabsf(fabsf(ld - pos) * s1 * s2 + ld);
      }
    }
  }
  float4 res;
#pragma unroll
  for (int e = 0; e < 4; e++) (&res.x)[e] = fminf(fmaxf(ov[e], lo), hi);
  *(float4*)(poutb + ((size_t)row << 10) + j0) = res;
  if (opt) {
    // write final positions directly in the packed-A image for gemm_k<2>
    // (K=1024 -> S=16): chunk = (row>>7)*16 + (j0>>6), elem within chunk =
    // (row&127)*64 + ((kq ^ (row&7))<<3) + (j0&7), kq = (j0>>3)&7
    ushort4 o4;
    o4.x = f2bf(res.x); o4.y = f2bf(res.y); o4.z = f2bf(res.z); o4.w = f2bf(res.w);
    const int rr = row & 127;
    const size_t chunk = (size_t)((row >> 7) << 4) + (j0 >> 6);
    ushort* dst = opt + (chunk << 13) + (rr << 6) + ((((j0 >> 3) & 7) ^ (rr & 7)) << 3) + (j0 & 7);
    *(ushort4*)dst = o4;
  }
}

// ================= host =================
extern "C" void kernel_launch(void* const* d_in, const int* in_sizes, int n_in,
                              void* d_out, int out_size, void* d_ws, size_t ws_size,
                              hipStream_t stream) {
  const float* inp = (const float*)d_in[0];   // input  [8192,1024]
  const float* adj = (const float*)d_in[1];   // adj    [8192,8192]
  const float* h0  = (const float*)d_in[2];   // h0     [8192,1024]
  const float* wgt = (const float*)d_in[3];   // weight [1024,1024]
  const float* lam = (const float*)d_in[4];   // lamda scalar
  const float* alp = (const float*)d_in[5];   // alpha scalar
  const int* lint  = (const int*)d_in[6];     // l scalar

  float* outp = (float*)d_out;

  char* ws = (char*)d_ws;
  // Apk (134.2MB) lives at ws+0 and is dead after gemm1; the whale ping/pong and
  // packed OPT overlay it afterwards (stream-ordered, no overlap in time).
  bf16t* Apk  = (bf16t*)(ws);               // 134.2MB packed adj (dead after gemm1)
  float* P0   = (float*)(ws);               // 33.6MB whale ping   (overlays Apk)
  float* P1   = (float*)(ws + 33554432);    // 33.6MB whale pong   (overlays Apk)
  ushort* OPT = (ushort*)(ws + 67108864);   // 16.8MB final positions, packed-A image
  bf16t* B1p  = (bf16t*)(ws + 134217728);   // 16.8MB packed input
  bf16t* Wp   = (bf16t*)(ws + 150994944);   // 2.1MB packed weight
  float* SUP  = (float*)(ws + 153092096);   // 33.6MB support (live to the end)
  float* PRT  = (float*)(ws + 186646528);   // partials (512 lo + 512 hi)
  float* BND  = (float*)(ws + 186662912);   // lower/upper

  // 1) pack adj (A-tile image, swizzled), input and weight (k-group-major)
  hipLaunchKernelGGL(packa_k, dim3(32768), dim3(256), 0, stream, adj, (uint4*)Apk, 8192, 8192, 7);
  hipLaunchKernelGGL(packb_k, dim3(4096), dim3(256), 0, stream, inp, (uint4*)B1p, 8192, 1024);
  hipLaunchKernelGGL(packb_k, dim3(512), dim3(256), 0, stream, wgt, (uint4*)Wp, 1024, 1024);
  // 2) support = (1-alpha)*(adj@input) + alpha*h0, + fused min/max partials
  hipLaunchKernelGGL((gemm_k<1>), dim3(512), dim3(256), 0, stream, Apk, B1p, h0, alp, lint,
                     SUP, PRT, 512, 1024, 8192);
  // 3) reduce 512 block partials -> lower/upper
  hipLaunchKernelGGL(minmax2_k, dim3(1), dim3(256), 0, stream, PRT, 512, BND);

  // 4) whale optimizer: key(42) = (0,42); split -> (k0, loop_key)
  u32 k0k[2], lpk[2];
  split2(0u, 42u, k0k, lpk);
  int ldr = scalar_randint8192(k0k[0], k0k[1]);
  const float* cur = SUP;
  float* bufs[2] = {P0, P1};
  for (int it = 0; it < 10; ++it) {
    u32 ka, kb; tf2(lpk[0], lpk[1], 0u, (u32)it, ka, kb);  // fold_in(loop_key, it)
    u32 ks[6][2];
    split6(ka, kb, ks);
    u32 k5A[2], k5B[2];
    split2(ks[4][0], ks[4][1], k5A, k5B);  // randint pre-split: use subkey2
    WA w;
    w.k1a = ks[0][0]; w.k1b = ks[0][1];
    w.k2a = ks[1][0]; w.k2b = ks[1][1];
    w.k3a = ks[2][0]; w.k3b = ks[2][1];
    w.k4a = ks[3][0]; w.k4b = ks[3][1];
    w.k5a = k5B[0];   w.k5b = k5B[1];
    w.ldr = ldr;
    const float itf = (float)it;
    w.a = 2.0f - itf * 0.2f;
    w.a2 = -1.0f + itf * (-0.1f);
    float* nxt = bufs[it & 1];
    hipLaunchKernelGGL(whale_k, dim3(8192), dim3(256), 0, stream, cur, nxt,
                       (it == 9) ? OPT : (ushort*)nullptr, BND, w);
    cur = nxt;
    ldr = scalar_randint8192(ks[5][0], ks[5][1]);  // leader index for next iter
  }
  // 5) out = theta*(opt@weight) + (1-theta)*support
  hipLaunchKernelGGL((gemm_k<2>), dim3(512), dim3(256), 0, stream, (const bf16t*)OPT, Wp, SUP, lam, lint,
                     outp, (float*)nullptr, 0, 1024, 1024);
  (void)in_sizes; (void)n_in; (void)out_size; (void)ws_size;
}